// Round 7
// baseline (700.158 us; speedup 1.0000x reference)
//
#include <hip/hip_runtime.h>
#include <hip/hip_bf16.h>

typedef __attribute__((ext_vector_type(8))) short short8;
typedef __attribute__((ext_vector_type(4))) short short4v;
typedef __attribute__((ext_vector_type(4))) float f32x4;

#define NB 8
#define NT 1024
#define NC 512
#define NHID 2048
#define NK 31
#define NH 4
#define NTP 994            // NT - NK + 1
#define MROWS (NB * NTP)   // 7952
#define TG 4               // t's per dynconv block

__device__ __forceinline__ void gload_lds16(const void* g, void* l) {
  __builtin_amdgcn_global_load_lds(
      (const __attribute__((address_space(1))) void*)g,
      (__attribute__((address_space(3))) void*)l, 16, 0, 0);
}

// ---------------------------------------------------------------------------
// prep_wc: Wc (O=2048, C=512, K=31) fp32 -> Wt tiles [obig][cb][k][or][ci]
//   tile = 256 o-rows x 64 ci, UNSWIZZLED (conv_gemm reads B direct from L2)
//   flat index: ((obig*8 + cb)*31 + k)*16384 + or*64 + ci
// ---------------------------------------------------------------------------
__global__ __launch_bounds__(256) void prep_wc(const float* __restrict__ Wc,
                                               __hip_bfloat16* __restrict__ Wt) {
  const int blk = blockIdx.x;
  const int cb = blk & 7;
  const int o0 = (blk >> 3) << 3;  // 8 o's per block
  const int c0 = cb << 6;
  const int obig = o0 >> 8;
  const int orb = o0 & 255;        // row base within 256-tile (mult of 8)
  __shared__ float lds[8 * 64 * NK];  // [ol][cl][k]  63.5KB
  for (int ol = 0; ol < 8; ++ol) {
    const float* src = Wc + ((size_t)(o0 + ol) * NC + c0) * NK;
    for (int i = threadIdx.x; i < 64 * NK; i += 256) lds[ol * (64 * NK) + i] = src[i];
  }
  __syncthreads();
  for (int i = threadIdx.x; i < NK * 8 * 64; i += 256) {
    const int k = i >> 9;          // /512
    const int rem = i & 511;
    const int ol = rem >> 6;
    const int ci = rem & 63;
    Wt[((size_t)((obig * 8 + cb) * NK + k) << 14) + ((orb + ol) << 6) + ci] =
        __float2bfloat16(lds[ol * (64 * NK) + ci * NK + k]);
  }
}

// ---------------------------------------------------------------------------
// prep_w2: W2 (C=512, HID=2048) fp32 -> W2t tiles [nb][kb][cr][oi']
//   tile = 128 c-rows x 64 oi, oi' = oi ^ ((cr&7)<<3)  (out_gemm LDS swizzle)
// ---------------------------------------------------------------------------
__global__ __launch_bounds__(256) void prep_w2(const float* __restrict__ W2,
                                               __hip_bfloat16* __restrict__ W2t) {
  const int i = blockIdx.x * 256 + threadIdx.x;  // over 32*512*64 = 1048576
  if (i < 32 * 512 * 64) {
    const int oi = i & 63;
    const int c = (i >> 6) & 511;
    const int kb = i >> 15;
    const size_t dst = ((size_t)(((c >> 7) * 32 + kb) * 128 + (c & 127)) << 6) +
                       (oi ^ ((c & 7) << 3));
    W2t[dst] = __float2bfloat16(W2[(size_t)c * NHID + (kb << 6) + oi]);
  }
}

// ---------------------------------------------------------------------------
// dynconv: 4 t's per block. y[b,t,c] = sum_j w[h,j]*x[b,t+j-15,c] + bias[c]
// Y stored bf16 (B,T,C), within each 64-ch block c' = c ^ ((t&7)<<3).
// v2: logits x-slice hoisted to registers (no LDS in hot loop);
//     gather via float4 (2 col-groups x 128 threads), 8B bf16x4 stores.
// ---------------------------------------------------------------------------
__global__ __launch_bounds__(256) void dynconv(const float* __restrict__ x,
                                               const float* __restrict__ Wl,
                                               const float* __restrict__ bl,
                                               const float* __restrict__ bias,
                                               __hip_bfloat16* __restrict__ Y) {
  const int t0 = blockIdx.x * TG;
  const int b = blockIdx.y;
  const int tid = threadIdx.x, lane = tid & 63, w = tid >> 6;
  __shared__ float xt[TG][NC];
  __shared__ float lg[TG][NH * NK];
  __shared__ float wsm[TG][NH][NK];

  {
    const float4* xsrc = (const float4*)(x + ((size_t)b * NT + t0) * NC);
    float4* xdst = (float4*)xt;
#pragma unroll
    for (int i = 0; i < 2; ++i) xdst[(i << 8) + tid] = xsrc[(i << 8) + tid];
  }
  __syncthreads();

  // hoist this lane's x-slice into registers (stays out of the 31-iter loop)
  float xv[TG][8];
#pragma unroll
  for (int tg = 0; tg < TG; ++tg)
#pragma unroll
    for (int u = 0; u < 8; ++u) xv[tg][u] = xt[tg][(lane << 3) + u];

  // logits: wave w handles ids w, w+4, ... (124 = 4 waves * 31)
  for (int i = 0; i < 31; ++i) {
    const int id = (i << 2) | w;  // 0..123
    const float* wrow = Wl + (size_t)id * NC + (lane << 3);
    float wv[8];
#pragma unroll
    for (int u = 0; u < 8; ++u) wv[u] = wrow[u];
    const float blv = bl[id];
#pragma unroll
    for (int tg = 0; tg < TG; ++tg) {
      float s = 0.f;
#pragma unroll
      for (int u = 0; u < 8; ++u) s += xv[tg][u] * wv[u];
#pragma unroll
      for (int off = 32; off; off >>= 1) s += __shfl_xor(s, off);
      if (lane == 0) lg[tg][id] = s + blv;
    }
  }
  __syncthreads();

  if (tid < TG * NH) {  // 16 threads: (tg,h)
    const int tg = tid >> 2, h = tid & 3;
    const int t = t0 + tg;
    int jlo = 15 - t; if (jlo < 0) jlo = 0;
    int jhi = 1038 - t; if (jhi > 30) jhi = 30;
    float mx = -1e30f;
    for (int j = jlo; j <= jhi; ++j) mx = fmaxf(mx, lg[tg][h * NK + j]);
    float ssum = 0.f;
    for (int j = 0; j < NK; ++j) {
      const float e = (j >= jlo && j <= jhi) ? __expf(lg[tg][h * NK + j] - mx) : 0.f;
      wsm[tg][h][j] = e;
      ssum += e;
    }
    const float inv = 1.f / ssum;
    for (int j = 0; j < NK; ++j) wsm[tg][h][j] *= inv;
  }
  __syncthreads();

  // gather: 2 groups x 128 threads; thread owns float4 (4 cols); tg += 2
  const int grp = tid >> 7;
  const int ct = tid & 127;
  const int c4 = ct << 2;
  const int h = c4 >> 7;
  const float4* x4 = (const float4*)x;
  const float4 b4 = ((const float4*)bias)[ct];
  for (int tg = grp; tg < TG; tg += 2) {
    const int t = t0 + tg;
    float a0 = 0.f, a1 = 0.f, a2 = 0.f, a3 = 0.f;
#pragma unroll
    for (int j = 0; j < NK; ++j) {
      int pos = t + j - 15;
      pos = pos < 0 ? 0 : (pos > NT - 1 ? NT - 1 : pos);  // OOB taps have w==0
      const float wgt = wsm[tg][h][j];
      const float4 v = x4[(((size_t)b * NT + pos) << 7) + ct];
      a0 += wgt * v.x; a1 += wgt * v.y; a2 += wgt * v.z; a3 += wgt * v.w;
    }
    const int cs = (c4 & ~63) | ((c4 & 63) ^ ((t & 7) << 3));  // 4-aligned preserved
    union { short4v s4; __hip_bfloat16 hh[4]; } u;
    u.hh[0] = __float2bfloat16(a0 + b4.x);
    u.hh[1] = __float2bfloat16(a1 + b4.y);
    u.hh[2] = __float2bfloat16(a2 + b4.z);
    u.hh[3] = __float2bfloat16(a3 + b4.w);
    *(short4v*)(Y + ((size_t)b * NT + t) * NC + cs) = u.s4;
  }
}

// ---------------------------------------------------------------------------
// conv_gemm v3: 256x256 tile, 8 waves (2Mx4N, per-wave 128x64), BK=64.
// B read DIRECTLY from Wt (global/L2) into registers -> no B LDS, no B
// barriers: the k-loop is BARRIER-FREE (Ys read-only per cb); waves
// desynchronize and cover each other's latencies. obig = blockIdx.x
// (fastest) -> same-panel blocks share an XCD L2 under round-robin.
// Epilogue: selu -> LDS transpose (reuse pool) -> coalesced 16B Z stores
// (fixes 2.5x write amplification of scattered scalar bf16 stores).
// Z swizzled, key = flattened row (b*NTP+tp)&7 (matches out_gemm).
// ---------------------------------------------------------------------------
__global__ __launch_bounds__(512, 2) void conv_gemm(const __hip_bfloat16* __restrict__ Y,
                                                    const __hip_bfloat16* __restrict__ Wt,
                                                    const float* __restrict__ bc,
                                                    __hip_bfloat16* __restrict__ Z) {
  const int o0 = blockIdx.x << 8;
  const int t0 = blockIdx.y << 8;
  const int b = blockIdx.z;
  __shared__ __align__(16) char pool[135168];   // Ys[288][64] then zt[256][264]
  __hip_bfloat16* Ys = (__hip_bfloat16*)pool;
  const int tid = threadIdx.x;
  const int lane = tid & 63, wid = tid >> 6;
  const int wr = wid >> 2, wcid = wid & 3;
  const int obig = o0 >> 8;
  const int l15 = lane & 15;
  const int kob = (lane >> 4) << 3;

  f32x4 acc[8][4] = {};

  auto stageY = [&](int cb_) {
    const int c0 = cb_ << 6;
#pragma unroll
    for (int p = 0; p < 5; ++p) {
      const int i = (p << 9) + tid;          // 2304 chunks of 16B = 288 rows
      if (i < 2304) {                        // wave-uniform predicate
        int grow = t0 + (i >> 3);
        if (grow > NT - 1) grow = NT - 1;    // feeds only discarded output rows
        gload_lds16(Y + (((size_t)b * NT + grow) << 9) + c0 + ((i & 7) << 3),
                    &Ys[i << 3]);
      }
    }
  };

  // per-lane B base inside Wt (unswizzled): row (wcid*64 + l15), col kob
  const __hip_bfloat16* wlane =
      Wt + (((size_t)(obig * 248)) << 14) + (((wcid << 6) + l15) << 6) + kob;

  stageY(0);
  __syncthreads();   // drains vmcnt(0): Ys(0) visible

  for (int cb = 0; cb < 8; ++cb) {
    for (int k = 0; k < NK; ++k) {
      const int s = cb * 31 + k;
      const __hip_bfloat16* wt = wlane + ((size_t)s << 14);
      short8 bv[2][4];
#pragma unroll
      for (int n = 0; n < 4; ++n) {
        bv[0][n] = *(const short8*)(wt + (n << 10));
        bv[1][n] = *(const short8*)(wt + (n << 10) + 32);
      }
      const int keyv = ((l15 + k) & 7) << 3;
      const int ako0 = kob ^ keyv;
      const int ako1 = (32 | kob) ^ keyv;
      const int arow = ((wr << 7) + l15 + k) << 6;
      short8 av[2][8];
#pragma unroll
      for (int m = 0; m < 8; ++m) {
        av[0][m] = *(const short8*)&Ys[arow + (m << 10) + ako0];
        av[1][m] = *(const short8*)&Ys[arow + (m << 10) + ako1];
      }
      __builtin_amdgcn_s_setprio(1);
#pragma unroll
      for (int kk = 0; kk < 2; ++kk)
#pragma unroll
        for (int m = 0; m < 8; ++m)
#pragma unroll
          for (int n = 0; n < 4; ++n)
            acc[m][n] = __builtin_amdgcn_mfma_f32_16x16x32_bf16(av[kk][m], bv[kk][n],
                                                                acc[m][n], 0, 0, 0);
      __builtin_amdgcn_s_setprio(0);
    }
    if (cb < 7) {
      __syncthreads();   // all waves done reading Ys(cb)
      stageY(cb + 1);
      __syncthreads();   // drains vmcnt(0): Ys(cb+1) visible
    }
  }

  // ---- epilogue: selu -> LDS transpose -> coalesced swizzled 16B stores
  __syncthreads();                                  // pool reusable
  __hip_bfloat16* zt = (__hip_bfloat16*)pool;       // [256][264] = 135,168 B
  const float kS = 1.0507009873554805f;
  const float kAS = 1.7580993408473766f;            // scale*alpha
#pragma unroll
  for (int n = 0; n < 4; ++n) {
    const int col = (wcid << 6) + (n << 4) + l15;
    const float bcv = bc[o0 + col];
#pragma unroll
    for (int m = 0; m < 8; ++m) {
      const int rb = (wr << 7) + (m << 4) + ((lane >> 4) << 2);
#pragma unroll
      for (int r = 0; r < 4; ++r) {
        const float v = acc[m][n][r] + bcv;
        const float sv = v > 0.f ? kS * v : kAS * (__expf(v) - 1.f);
        zt[(rb + r) * 264 + col] = __float2bfloat16(sv);
      }
    }
  }
  __syncthreads();
  for (int j = tid; j < 8192; j += 512) {   // 256 rows x 32 chunks of 16B
    const int row = j >> 5;
    const int c8 = (j & 31) << 3;
    const int tp = t0 + row;
    if (tp < NTP) {
      const size_t grow = (size_t)b * NTP + tp;
      const int key = ((int)grow & 7) << 3;
      const int cs = (c8 & ~63) | ((c8 & 63) ^ key);   // 8-aligned preserved
      *(short8*)(Z + grow * NHID + o0 + cs) = *(const short8*)&zt[row * 264 + c8];
    }
  }
}

// ---------------------------------------------------------------------------
// out_gemm: Out[row,c] = sum_o Z[row,o]*W2[c,o] + b2[c]  (fp32), M=7952,N=512,K=2048
// v2: double-buffered A+B (64 KB -> 2 blocks/CU), ONE barrier per step;
// __syncthreads' implicit vmcnt(0) drain covers the depth-1 prefetch.
// ---------------------------------------------------------------------------
__global__ __launch_bounds__(256) void out_gemm(const __hip_bfloat16* __restrict__ Zm,
                                                const __hip_bfloat16* __restrict__ W2t,
                                                const float* __restrict__ b2,
                                                float* __restrict__ Out) {
  const int n0 = blockIdx.x << 7;
  const int m0 = blockIdx.y << 7;
  __shared__ __align__(16) __hip_bfloat16 As[2][128 * 64];
  __shared__ __align__(16) __hip_bfloat16 Bs[2][128 * 64];
  const int tid = threadIdx.x;
  const int lane = tid & 63, wid = tid >> 6;
  const int wr = wid >> 1, wc = wid & 1;

  auto stage = [&](int bufi, int kb_) {
#pragma unroll
    for (int p = 0; p < 4; ++p) {
      const int i = (p << 8) + tid;
      int row = m0 + (i >> 3);
      if (row > MROWS - 1) row = MROWS - 1;  // discarded rows only
      gload_lds16(Zm + ((size_t)row << 11) + (kb_ << 6) + ((i & 7) << 3),
                  &As[bufi][i << 3]);
    }
    const __hip_bfloat16* wb = W2t + ((size_t)((n0 >> 7) * 32 + kb_) << 13);
#pragma unroll
    for (int p = 0; p < 4; ++p) {
      const int i = (p << 8) + tid;
      gload_lds16(wb + (i << 3), &Bs[bufi][i << 3]);
    }
  };

  f32x4 acc[4][4] = {};
  stage(0, 0);

  for (int kb = 0; kb < 32; ++kb) {
    const int buf = kb & 1;
    __syncthreads();                 // drains vmcnt(0): stage(kb) landed; prior reads done
    if (kb < 31) stage(buf ^ 1, kb + 1);
#pragma unroll
    for (int kk = 0; kk < 2; ++kk) {
      const int ko = (kk << 5) + ((lane >> 4) << 3);
      short8 av[4], bv[4];
#pragma unroll
      for (int m = 0; m < 4; ++m) {
        const int r = (wr << 6) + (m << 4) + (lane & 15);
        av[m] = *(const short8*)&As[buf][(r << 6) + (ko ^ ((r & 7) << 3))];
      }
#pragma unroll
      for (int n = 0; n < 4; ++n) {
        const int br = (wc << 6) + (n << 4) + (lane & 15);
        bv[n] = *(const short8*)&Bs[buf][(br << 6) + (ko ^ ((br & 7) << 3))];
      }
#pragma unroll
      for (int m = 0; m < 4; ++m)
#pragma unroll
        for (int n = 0; n < 4; ++n)
          acc[m][n] = __builtin_amdgcn_mfma_f32_16x16x32_bf16(av[m], bv[n], acc[m][n], 0, 0, 0);
    }
  }

#pragma unroll
  for (int n = 0; n < 4; ++n) {
    const int col = n0 + (wc << 6) + (n << 4) + (lane & 15);
    const float b2v = b2[col];
#pragma unroll
    for (int m = 0; m < 4; ++m) {
      const int rbase = m0 + (wr << 6) + (m << 4) + ((lane >> 4) << 2);
#pragma unroll
      for (int r = 0; r < 4; ++r) {
        const int row = rbase + r;
        if (row < MROWS) Out[(size_t)row * NC + col] = acc[m][n][r] + b2v;
      }
    }
  }
}

// ---------------------------------------------------------------------------
extern "C" void kernel_launch(void* const* d_in, const int* in_sizes, int n_in,
                              void* d_out, int out_size, void* d_ws, size_t ws_size,
                              hipStream_t stream) {
  const float* x = (const float*)d_in[0];
  const float* Wl = (const float*)d_in[1];
  const float* bl = (const float*)d_in[2];
  const float* bias = (const float*)d_in[3];
  const float* Wc = (const float*)d_in[4];
  const float* bc = (const float*)d_in[5];
  const float* W2 = (const float*)d_in[6];
  const float* b2 = (const float*)d_in[7];
  float* out = (float*)d_out;

  char* ws = (char*)d_ws;
  __hip_bfloat16* Wt = (__hip_bfloat16*)(ws);                    // 31*8*2048*64*2 = 65,011,712
  __hip_bfloat16* Y = (__hip_bfloat16*)(ws + 65011712);          // 8*1024*512*2   =  8,388,608
  __hip_bfloat16* W2t = (__hip_bfloat16*)(ws + 73400320);        // 32*512*64*2    =  2,097,152
  __hip_bfloat16* Z = (__hip_bfloat16*)(ws + 75497472);          // 8*994*2048*2   = 32,571,392

  hipLaunchKernelGGL(prep_wc, dim3(2048), dim3(256), 0, stream, Wc, Wt);
  hipLaunchKernelGGL(prep_w2, dim3(4096), dim3(256), 0, stream, W2, W2t);
  hipLaunchKernelGGL(dynconv, dim3(NT / TG, NB), dim3(256), 0, stream, x, Wl, bl, bias, Y);
  hipLaunchKernelGGL(conv_gemm, dim3(NHID / 256, 4, NB), dim3(512), 0, stream, Y, Wt, bc, Z);
  hipLaunchKernelGGL(out_gemm, dim3(NC / 128, (MROWS + 127) / 128), dim3(256), 0, stream,
                     Z, W2t, b2, out);
}

// Round 8
// 695.831 us; speedup vs baseline: 1.0062x; 1.0062x over previous
//
#include <hip/hip_runtime.h>
#include <hip/hip_bf16.h>

typedef __attribute__((ext_vector_type(8))) short short8;
typedef __attribute__((ext_vector_type(4))) short short4v;
typedef __attribute__((ext_vector_type(4))) float f32x4;

#define NB 8
#define NT 1024
#define NC 512
#define NHID 2048
#define NK 31
#define NH 4
#define NTP 994            // NT - NK + 1
#define MROWS (NB * NTP)   // 7952
#define TG 4               // t's per dynconv block

__device__ __forceinline__ void gload_lds16(const void* g, void* l) {
  __builtin_amdgcn_global_load_lds(
      (const __attribute__((address_space(1))) void*)g,
      (__attribute__((address_space(3))) void*)l, 16, 0, 0);
}

// ---------------------------------------------------------------------------
// prep_wc: Wc (O=2048, C=512, K=31) fp32 -> Wt tiles [obig][cb][k][or][ci]
//   tile = 256 o-rows x 64 ci, UNSWIZZLED (conv_gemm reads B direct from L2)
// ---------------------------------------------------------------------------
__global__ __launch_bounds__(256) void prep_wc(const float* __restrict__ Wc,
                                               __hip_bfloat16* __restrict__ Wt) {
  const int blk = blockIdx.x;
  const int cb = blk & 7;
  const int o0 = (blk >> 3) << 3;  // 8 o's per block
  const int c0 = cb << 6;
  const int obig = o0 >> 8;
  const int orb = o0 & 255;        // row base within 256-tile (mult of 8)
  __shared__ float lds[8 * 64 * NK];  // [ol][cl][k]  63.5KB
  for (int ol = 0; ol < 8; ++ol) {
    const float* src = Wc + ((size_t)(o0 + ol) * NC + c0) * NK;
    for (int i = threadIdx.x; i < 64 * NK; i += 256) lds[ol * (64 * NK) + i] = src[i];
  }
  __syncthreads();
  for (int i = threadIdx.x; i < NK * 8 * 64; i += 256) {
    const int k = i >> 9;          // /512
    const int rem = i & 511;
    const int ol = rem >> 6;
    const int ci = rem & 63;
    Wt[((size_t)((obig * 8 + cb) * NK + k) << 14) + ((orb + ol) << 6) + ci] =
        __float2bfloat16(lds[ol * (64 * NK) + ci * NK + k]);
  }
}

// ---------------------------------------------------------------------------
// prep_w2: W2 (C=512, HID=2048) fp32 -> W2t tiles [nb][kb][cr][oi']
//   tile = 128 c-rows x 64 oi, oi' = oi ^ ((cr&7)<<3)  (out_gemm LDS swizzle)
// ---------------------------------------------------------------------------
__global__ __launch_bounds__(256) void prep_w2(const float* __restrict__ W2,
                                               __hip_bfloat16* __restrict__ W2t) {
  const int i = blockIdx.x * 256 + threadIdx.x;  // over 32*512*64 = 1048576
  if (i < 32 * 512 * 64) {
    const int oi = i & 63;
    const int c = (i >> 6) & 511;
    const int kb = i >> 15;
    const size_t dst = ((size_t)(((c >> 7) * 32 + kb) * 128 + (c & 127)) << 6) +
                       (oi ^ ((c & 7) << 3));
    W2t[dst] = __float2bfloat16(W2[(size_t)c * NHID + (kb << 6) + oi]);
  }
}

// ---------------------------------------------------------------------------
// dynconv: 4 t's per block. y[b,t,c] = sum_j w[h,j]*x[b,t+j-15,c] + bias[c]
// Y stored bf16 (B,T,C), within each 64-ch block c' = c ^ ((t&7)<<3).
// ---------------------------------------------------------------------------
__global__ __launch_bounds__(256) void dynconv(const float* __restrict__ x,
                                               const float* __restrict__ Wl,
                                               const float* __restrict__ bl,
                                               const float* __restrict__ bias,
                                               __hip_bfloat16* __restrict__ Y) {
  const int t0 = blockIdx.x * TG;
  const int b = blockIdx.y;
  const int tid = threadIdx.x, lane = tid & 63, w = tid >> 6;
  __shared__ float xt[TG][NC];
  __shared__ float lg[TG][NH * NK];
  __shared__ float wsm[TG][NH][NK];

  {
    const float4* xsrc = (const float4*)(x + ((size_t)b * NT + t0) * NC);
    float4* xdst = (float4*)xt;
#pragma unroll
    for (int i = 0; i < 2; ++i) xdst[(i << 8) + tid] = xsrc[(i << 8) + tid];
  }
  __syncthreads();

  float xv[TG][8];
#pragma unroll
  for (int tg = 0; tg < TG; ++tg)
#pragma unroll
    for (int u = 0; u < 8; ++u) xv[tg][u] = xt[tg][(lane << 3) + u];

  for (int i = 0; i < 31; ++i) {
    const int id = (i << 2) | w;  // 0..123
    const float* wrow = Wl + (size_t)id * NC + (lane << 3);
    float wv[8];
#pragma unroll
    for (int u = 0; u < 8; ++u) wv[u] = wrow[u];
    const float blv = bl[id];
#pragma unroll
    for (int tg = 0; tg < TG; ++tg) {
      float s = 0.f;
#pragma unroll
      for (int u = 0; u < 8; ++u) s += xv[tg][u] * wv[u];
#pragma unroll
      for (int off = 32; off; off >>= 1) s += __shfl_xor(s, off);
      if (lane == 0) lg[tg][id] = s + blv;
    }
  }
  __syncthreads();

  if (tid < TG * NH) {  // 16 threads: (tg,h)
    const int tg = tid >> 2, h = tid & 3;
    const int t = t0 + tg;
    int jlo = 15 - t; if (jlo < 0) jlo = 0;
    int jhi = 1038 - t; if (jhi > 30) jhi = 30;
    float mx = -1e30f;
    for (int j = jlo; j <= jhi; ++j) mx = fmaxf(mx, lg[tg][h * NK + j]);
    float ssum = 0.f;
    for (int j = 0; j < NK; ++j) {
      const float e = (j >= jlo && j <= jhi) ? __expf(lg[tg][h * NK + j] - mx) : 0.f;
      wsm[tg][h][j] = e;
      ssum += e;
    }
    const float inv = 1.f / ssum;
    for (int j = 0; j < NK; ++j) wsm[tg][h][j] *= inv;
  }
  __syncthreads();

  const int grp = tid >> 7;
  const int ct = tid & 127;
  const int c4 = ct << 2;
  const int h = c4 >> 7;
  const float4* x4 = (const float4*)x;
  const float4 b4 = ((const float4*)bias)[ct];
  for (int tg = grp; tg < TG; tg += 2) {
    const int t = t0 + tg;
    float a0 = 0.f, a1 = 0.f, a2 = 0.f, a3 = 0.f;
#pragma unroll
    for (int j = 0; j < NK; ++j) {
      int pos = t + j - 15;
      pos = pos < 0 ? 0 : (pos > NT - 1 ? NT - 1 : pos);  // OOB taps have w==0
      const float wgt = wsm[tg][h][j];
      const float4 v = x4[(((size_t)b * NT + pos) << 7) + ct];
      a0 += wgt * v.x; a1 += wgt * v.y; a2 += wgt * v.z; a3 += wgt * v.w;
    }
    const int cs = (c4 & ~63) | ((c4 & 63) ^ ((t & 7) << 3));  // 4-aligned preserved
    union { short4v s4; __hip_bfloat16 hh[4]; } u;
    u.hh[0] = __float2bfloat16(a0 + b4.x);
    u.hh[1] = __float2bfloat16(a1 + b4.y);
    u.hh[2] = __float2bfloat16(a2 + b4.z);
    u.hh[3] = __float2bfloat16(a3 + b4.w);
    *(short4v*)(Y + ((size_t)b * NT + t) * NC + cs) = u.s4;
  }
}

// ---------------------------------------------------------------------------
// conv_gemm v4: 256x256 tile, 8 waves (2Mx4N, per-wave 128x64), BK=64.
// B direct from Wt (L2) with REGISTER PING-PONG PREFETCH (depth 1):
//   step s issues B(s+1) into the spare array (all static indices via
//   macro-expanded pair loop), consumes B(s) loaded one full step earlier
//   -> compiler's dep-tracked wait is vmcnt(8), hidden under ~4000 cyc of
//   MFMA. sched_barrier(0) pins the issue above the MFMA cluster.
// k-loop barrier-free (Ys read-only per cb); A-frags in half-tiles (av
// reused) to stay <=256 unified regs (2 waves/SIMD).
// Epilogue: selu -> LDS transpose -> coalesced swizzled 16B stores.
// ---------------------------------------------------------------------------
__global__ __launch_bounds__(512, 2) void conv_gemm(const __hip_bfloat16* __restrict__ Y,
                                                    const __hip_bfloat16* __restrict__ Wt,
                                                    const float* __restrict__ bc,
                                                    __hip_bfloat16* __restrict__ Z) {
  const int o0 = blockIdx.x << 8;
  const int t0 = blockIdx.y << 8;
  const int b = blockIdx.z;
  __shared__ __align__(16) char pool[135168];   // Ys[288][64] then zt[256][264]
  __hip_bfloat16* Ys = (__hip_bfloat16*)pool;
  const int tid = threadIdx.x;
  const int lane = tid & 63, wid = tid >> 6;
  const int wr = wid >> 2, wcid = wid & 3;
  const int obig = o0 >> 8;
  const int l15 = lane & 15;
  const int kob = (lane >> 4) << 3;

  f32x4 acc[8][4] = {};

  auto stageY = [&](int cb_) {
    const int c0 = cb_ << 6;
#pragma unroll
    for (int p = 0; p < 5; ++p) {
      const int i = (p << 9) + tid;          // 2304 chunks of 16B = 288 rows
      if (i < 2304) {                        // wave-uniform predicate
        int grow = t0 + (i >> 3);
        if (grow > NT - 1) grow = NT - 1;    // feeds only discarded output rows
        gload_lds16(Y + (((size_t)b * NT + grow) << 9) + c0 + ((i & 7) << 3),
                    &Ys[i << 3]);
      }
    }
  };

  // per-lane B base inside Wt (unswizzled): row (wcid*64 + l15), col kob
  const __hip_bfloat16* wlane =
      Wt + (((size_t)(obig * 248)) << 14) + (((wcid << 6) + l15) << 6) + kob;

  auto issueB = [&](short8 (&dst)[2][4], int s_) {
    const __hip_bfloat16* wt = wlane + ((size_t)s_ << 14);
#pragma unroll
    for (int n = 0; n < 4; ++n) {
      dst[0][n] = *(const short8*)(wt + (n << 10));
      dst[1][n] = *(const short8*)(wt + (n << 10) + 32);
    }
  };

  stageY(0);
  short8 bva[2][4], bvb[2][4];
  issueB(bva, 0);     // B(0)
  __syncthreads();    // drains vmcnt(0): Ys(0) + B(0) landed

  int cb = 0, k = 0;

#define CG_STEP(USE, LOAD)                                                    \
  do {                                                                        \
    const int s_ = cb * NK + k;                                               \
    if (s_ < 247) issueB(LOAD, s_ + 1); /* prefetch B(s+1), in flight */      \
    __builtin_amdgcn_sched_barrier(0);                                        \
    const int keyv = ((l15 + k) & 7) << 3;                                    \
    const int ako0 = kob ^ keyv;                                              \
    const int ako1 = (32 | kob) ^ keyv;                                       \
    const int arow = ((wr << 7) + l15 + k) << 6;                              \
    short8 av0[4], av1[4];                                                    \
    _Pragma("unroll")                                                         \
    for (int m = 0; m < 4; ++m) {                                             \
      av0[m] = *(const short8*)&Ys[arow + (m << 10) + ako0];                  \
      av1[m] = *(const short8*)&Ys[arow + (m << 10) + ako1];                  \
    }                                                                         \
    __builtin_amdgcn_s_setprio(1);                                            \
    _Pragma("unroll")                                                         \
    for (int m = 0; m < 4; ++m)                                               \
      _Pragma("unroll")                                                       \
      for (int n = 0; n < 4; ++n) {                                           \
        acc[m][n] = __builtin_amdgcn_mfma_f32_16x16x32_bf16(av0[m], USE[0][n],\
                                                            acc[m][n], 0, 0, 0);\
        acc[m][n] = __builtin_amdgcn_mfma_f32_16x16x32_bf16(av1[m], USE[1][n],\
                                                            acc[m][n], 0, 0, 0);\
      }                                                                       \
    __builtin_amdgcn_s_setprio(0);                                            \
    _Pragma("unroll")                                                         \
    for (int m = 0; m < 4; ++m) {                                             \
      av0[m] = *(const short8*)&Ys[arow + 4096 + (m << 10) + ako0];           \
      av1[m] = *(const short8*)&Ys[arow + 4096 + (m << 10) + ako1];           \
    }                                                                         \
    __builtin_amdgcn_s_setprio(1);                                            \
    _Pragma("unroll")                                                         \
    for (int m = 0; m < 4; ++m)                                               \
      _Pragma("unroll")                                                       \
      for (int n = 0; n < 4; ++n) {                                           \
        acc[4 + m][n] = __builtin_amdgcn_mfma_f32_16x16x32_bf16(              \
            av0[m], USE[0][n], acc[4 + m][n], 0, 0, 0);                       \
        acc[4 + m][n] = __builtin_amdgcn_mfma_f32_16x16x32_bf16(              \
            av1[m], USE[1][n], acc[4 + m][n], 0, 0, 0);                       \
      }                                                                       \
    __builtin_amdgcn_s_setprio(0);                                            \
  } while (0)

#define CG_ADV()                                         \
  do {                                                   \
    ++k;                                                 \
    if (k == NK) {                                       \
      k = 0; ++cb;                                       \
      if (cb < 8) {                                      \
        __syncthreads(); /* all waves done with Ys(cb-1) */ \
        stageY(cb);                                      \
        __syncthreads(); /* Ys(cb) visible (vmcnt drained) */ \
      }                                                  \
    }                                                    \
  } while (0)

  for (int it = 0; it < 124; ++it) {  // 248 steps, ping-pong pairs
    CG_STEP(bva, bvb);
    CG_ADV();
    CG_STEP(bvb, bva);
    CG_ADV();
  }
#undef CG_STEP
#undef CG_ADV

  // ---- epilogue: selu -> LDS transpose -> coalesced swizzled 16B stores
  __syncthreads();                                  // pool reusable
  __hip_bfloat16* zt = (__hip_bfloat16*)pool;       // [256][264] = 135,168 B
  const float kS = 1.0507009873554805f;
  const float kAS = 1.7580993408473766f;            // scale*alpha
#pragma unroll
  for (int n = 0; n < 4; ++n) {
    const int col = (wcid << 6) + (n << 4) + l15;
    const float bcv = bc[o0 + col];
#pragma unroll
    for (int m = 0; m < 8; ++m) {
      const int rb = (wr << 7) + (m << 4) + ((lane >> 4) << 2);
#pragma unroll
      for (int r = 0; r < 4; ++r) {
        const float v = acc[m][n][r] + bcv;
        const float sv = v > 0.f ? kS * v : kAS * (__expf(v) - 1.f);
        zt[(rb + r) * 264 + col] = __float2bfloat16(sv);
      }
    }
  }
  __syncthreads();
  for (int j = tid; j < 8192; j += 512) {   // 256 rows x 32 chunks of 16B
    const int row = j >> 5;
    const int c8 = (j & 31) << 3;
    const int tp = t0 + row;
    if (tp < NTP) {
      const size_t grow = (size_t)b * NTP + tp;
      const int key = ((int)grow & 7) << 3;
      const int cs = (c8 & ~63) | ((c8 & 63) ^ key);   // 8-aligned preserved
      *(short8*)(Z + grow * NHID + o0 + cs) = *(const short8*)&zt[row * 264 + c8];
    }
  }
}

// ---------------------------------------------------------------------------
// out_gemm: Out[row,c] = sum_o Z[row,o]*W2[c,o] + b2[c]  (fp32), M=7952,N=512,K=2048
// double-buffered A+B, one barrier per step.
// ---------------------------------------------------------------------------
__global__ __launch_bounds__(256) void out_gemm(const __hip_bfloat16* __restrict__ Zm,
                                                const __hip_bfloat16* __restrict__ W2t,
                                                const float* __restrict__ b2,
                                                float* __restrict__ Out) {
  const int n0 = blockIdx.x << 7;
  const int m0 = blockIdx.y << 7;
  __shared__ __align__(16) __hip_bfloat16 As[2][128 * 64];
  __shared__ __align__(16) __hip_bfloat16 Bs[2][128 * 64];
  const int tid = threadIdx.x;
  const int lane = tid & 63, wid = tid >> 6;
  const int wr = wid >> 1, wc = wid & 1;

  auto stage = [&](int bufi, int kb_) {
#pragma unroll
    for (int p = 0; p < 4; ++p) {
      const int i = (p << 8) + tid;
      int row = m0 + (i >> 3);
      if (row > MROWS - 1) row = MROWS - 1;  // discarded rows only
      gload_lds16(Zm + ((size_t)row << 11) + (kb_ << 6) + ((i & 7) << 3),
                  &As[bufi][i << 3]);
    }
    const __hip_bfloat16* wb = W2t + ((size_t)((n0 >> 7) * 32 + kb_) << 13);
#pragma unroll
    for (int p = 0; p < 4; ++p) {
      const int i = (p << 8) + tid;
      gload_lds16(wb + (i << 3), &Bs[bufi][i << 3]);
    }
  };

  f32x4 acc[4][4] = {};
  stage(0, 0);

  for (int kb = 0; kb < 32; ++kb) {
    const int buf = kb & 1;
    __syncthreads();                 // drains vmcnt(0): stage(kb) landed; prior reads done
    if (kb < 31) stage(buf ^ 1, kb + 1);
#pragma unroll
    for (int kk = 0; kk < 2; ++kk) {
      const int ko = (kk << 5) + ((lane >> 4) << 3);
      short8 av[4], bv[4];
#pragma unroll
      for (int m = 0; m < 4; ++m) {
        const int r = (wr << 6) + (m << 4) + (lane & 15);
        av[m] = *(const short8*)&As[buf][(r << 6) + (ko ^ ((r & 7) << 3))];
      }
#pragma unroll
      for (int n = 0; n < 4; ++n) {
        const int br = (wc << 6) + (n << 4) + (lane & 15);
        bv[n] = *(const short8*)&Bs[buf][(br << 6) + (ko ^ ((br & 7) << 3))];
      }
#pragma unroll
      for (int m = 0; m < 4; ++m)
#pragma unroll
        for (int n = 0; n < 4; ++n)
          acc[m][n] = __builtin_amdgcn_mfma_f32_16x16x32_bf16(av[m], bv[n], acc[m][n], 0, 0, 0);
    }
  }

#pragma unroll
  for (int n = 0; n < 4; ++n) {
    const int col = n0 + (wc << 6) + (n << 4) + (lane & 15);
    const float b2v = b2[col];
#pragma unroll
    for (int m = 0; m < 4; ++m) {
      const int rbase = m0 + (wr << 6) + (m << 4) + ((lane >> 4) << 2);
#pragma unroll
      for (int r = 0; r < 4; ++r) {
        const int row = rbase + r;
        if (row < MROWS) Out[(size_t)row * NC + col] = acc[m][n][r] + b2v;
      }
    }
  }
}

// ---------------------------------------------------------------------------
extern "C" void kernel_launch(void* const* d_in, const int* in_sizes, int n_in,
                              void* d_out, int out_size, void* d_ws, size_t ws_size,
                              hipStream_t stream) {
  const float* x = (const float*)d_in[0];
  const float* Wl = (const float*)d_in[1];
  const float* bl = (const float*)d_in[2];
  const float* bias = (const float*)d_in[3];
  const float* Wc = (const float*)d_in[4];
  const float* bc = (const float*)d_in[5];
  const float* W2 = (const float*)d_in[6];
  const float* b2 = (const float*)d_in[7];
  float* out = (float*)d_out;

  char* ws = (char*)d_ws;
  __hip_bfloat16* Wt = (__hip_bfloat16*)(ws);                    // 31*8*2048*64*2 = 65,011,712
  __hip_bfloat16* Y = (__hip_bfloat16*)(ws + 65011712);          // 8*1024*512*2   =  8,388,608
  __hip_bfloat16* W2t = (__hip_bfloat16*)(ws + 73400320);        // 32*512*64*2    =  2,097,152
  __hip_bfloat16* Z = (__hip_bfloat16*)(ws + 75497472);          // 8*994*2048*2   = 32,571,392

  hipLaunchKernelGGL(prep_wc, dim3(2048), dim3(256), 0, stream, Wc, Wt);
  hipLaunchKernelGGL(prep_w2, dim3(4096), dim3(256), 0, stream, W2, W2t);
  hipLaunchKernelGGL(dynconv, dim3(NT / TG, NB), dim3(256), 0, stream, x, Wl, bl, bias, Y);
  hipLaunchKernelGGL(conv_gemm, dim3(NHID / 256, 4, NB), dim3(512), 0, stream, Y, Wt, bc, Z);
  hipLaunchKernelGGL(out_gemm, dim3(NC / 128, (MROWS + 127) / 128), dim3(256), 0, stream,
                     Z, W2t, b2, out);
}

// Round 9
// 577.166 us; speedup vs baseline: 1.2131x; 1.2056x over previous
//
#include <hip/hip_runtime.h>
#include <hip/hip_bf16.h>

typedef __attribute__((ext_vector_type(8))) short short8;
typedef __attribute__((ext_vector_type(4))) short short4v;
typedef __attribute__((ext_vector_type(4))) float f32x4;

#define NB 8
#define NT 1024
#define NC 512
#define NHID 2048
#define NK 31
#define NH 4
#define NTP 994            // NT - NK + 1
#define MROWS (NB * NTP)   // 7952
#define TG 4               // t's per dynconv block

__device__ __forceinline__ void gload_lds16(const void* g, void* l) {
  __builtin_amdgcn_global_load_lds(
      (const __attribute__((address_space(1))) void*)g,
      (__attribute__((address_space(3))) void*)l, 16, 0, 0);
}

#define FENCE() __builtin_amdgcn_sched_barrier(0)
#define SBAR()                                  \
  do {                                          \
    FENCE();                                    \
    __builtin_amdgcn_s_barrier();               \
    FENCE();                                    \
  } while (0)
#define WLGKM(n)                                                 \
  do {                                                           \
    FENCE();                                                     \
    asm volatile("s_waitcnt lgkmcnt(" #n ")" ::: "memory");      \
    FENCE();                                                     \
  } while (0)
#define WVM(n)                                                   \
  do {                                                           \
    FENCE();                                                     \
    asm volatile("s_waitcnt vmcnt(" #n ")" ::: "memory");        \
    FENCE();                                                     \
  } while (0)

// ---------------------------------------------------------------------------
// prep_wc: Wc (O=2048, C=512, K=31) fp32 -> Wt tiles [obig][cb][k][or][ci']
//   tile = 256 o-rows x 64 ci, ci' = ci ^ ((or&7)<<3)  (T2 swizzle baked in)
// ---------------------------------------------------------------------------
__global__ __launch_bounds__(256) void prep_wc(const float* __restrict__ Wc,
                                               __hip_bfloat16* __restrict__ Wt) {
  const int blk = blockIdx.x;
  const int cb = blk & 7;
  const int o0 = (blk >> 3) << 3;  // 8 o's per block
  const int c0 = cb << 6;
  const int obig = o0 >> 8;
  const int orb = o0 & 255;        // row base within 256-tile (mult of 8)
  __shared__ float lds[8 * 64 * NK];  // [ol][cl][k]  63.5KB
  for (int ol = 0; ol < 8; ++ol) {
    const float* src = Wc + ((size_t)(o0 + ol) * NC + c0) * NK;
    for (int i = threadIdx.x; i < 64 * NK; i += 256) lds[ol * (64 * NK) + i] = src[i];
  }
  __syncthreads();
  for (int i = threadIdx.x; i < NK * 8 * 64; i += 256) {
    const int k = i >> 9;          // /512
    const int rem = i & 511;
    const int ol = rem >> 6;
    const int ci = rem & 63;
    Wt[((size_t)((obig * 8 + cb) * NK + k) << 14) + ((orb + ol) << 6) + (ci ^ (ol << 3))] =
        __float2bfloat16(lds[ol * (64 * NK) + ci * NK + k]);
  }
}

// ---------------------------------------------------------------------------
// prep_w2: W2 (C=512, HID=2048) fp32 -> W2t tiles [nb][kb][cr][oi']
//   tile = 128 c-rows x 64 oi, oi' = oi ^ ((cr&7)<<3)  (out_gemm LDS swizzle)
// ---------------------------------------------------------------------------
__global__ __launch_bounds__(256) void prep_w2(const float* __restrict__ W2,
                                               __hip_bfloat16* __restrict__ W2t) {
  const int i = blockIdx.x * 256 + threadIdx.x;  // over 32*512*64 = 1048576
  if (i < 32 * 512 * 64) {
    const int oi = i & 63;
    const int c = (i >> 6) & 511;
    const int kb = i >> 15;
    const size_t dst = ((size_t)(((c >> 7) * 32 + kb) * 128 + (c & 127)) << 6) +
                       (oi ^ ((c & 7) << 3));
    W2t[dst] = __float2bfloat16(W2[(size_t)c * NHID + (kb << 6) + oi]);
  }
}

// ---------------------------------------------------------------------------
// dynconv: 4 t's per block. y[b,t,c] = sum_j w[h,j]*x[b,t+j-15,c] + bias[c]
// Y stored bf16 (B,T,C), within each 64-ch block c' = c ^ ((t&7)<<3).
// ---------------------------------------------------------------------------
__global__ __launch_bounds__(256) void dynconv(const float* __restrict__ x,
                                               const float* __restrict__ Wl,
                                               const float* __restrict__ bl,
                                               const float* __restrict__ bias,
                                               __hip_bfloat16* __restrict__ Y) {
  const int t0 = blockIdx.x * TG;
  const int b = blockIdx.y;
  const int tid = threadIdx.x, lane = tid & 63, w = tid >> 6;
  __shared__ float xt[TG][NC];
  __shared__ float lg[TG][NH * NK];
  __shared__ float wsm[TG][NH][NK];

  {
    const float4* xsrc = (const float4*)(x + ((size_t)b * NT + t0) * NC);
    float4* xdst = (float4*)xt;
#pragma unroll
    for (int i = 0; i < 2; ++i) xdst[(i << 8) + tid] = xsrc[(i << 8) + tid];
  }
  __syncthreads();

  float xv[TG][8];
#pragma unroll
  for (int tg = 0; tg < TG; ++tg)
#pragma unroll
    for (int u = 0; u < 8; ++u) xv[tg][u] = xt[tg][(lane << 3) + u];

  for (int i = 0; i < 31; ++i) {
    const int id = (i << 2) | w;  // 0..123
    const float* wrow = Wl + (size_t)id * NC + (lane << 3);
    float wv[8];
#pragma unroll
    for (int u = 0; u < 8; ++u) wv[u] = wrow[u];
    const float blv = bl[id];
#pragma unroll
    for (int tg = 0; tg < TG; ++tg) {
      float s = 0.f;
#pragma unroll
      for (int u = 0; u < 8; ++u) s += xv[tg][u] * wv[u];
#pragma unroll
      for (int off = 32; off; off >>= 1) s += __shfl_xor(s, off);
      if (lane == 0) lg[tg][id] = s + blv;
    }
  }
  __syncthreads();

  if (tid < TG * NH) {  // 16 threads: (tg,h)
    const int tg = tid >> 2, h = tid & 3;
    const int t = t0 + tg;
    int jlo = 15 - t; if (jlo < 0) jlo = 0;
    int jhi = 1038 - t; if (jhi > 30) jhi = 30;
    float mx = -1e30f;
    for (int j = jlo; j <= jhi; ++j) mx = fmaxf(mx, lg[tg][h * NK + j]);
    float ssum = 0.f;
    for (int j = 0; j < NK; ++j) {
      const float e = (j >= jlo && j <= jhi) ? __expf(lg[tg][h * NK + j] - mx) : 0.f;
      wsm[tg][h][j] = e;
      ssum += e;
    }
    const float inv = 1.f / ssum;
    for (int j = 0; j < NK; ++j) wsm[tg][h][j] *= inv;
  }
  __syncthreads();

  const int grp = tid >> 7;
  const int ct = tid & 127;
  const int c4 = ct << 2;
  const int h = c4 >> 7;
  const float4* x4 = (const float4*)x;
  const float4 b4 = ((const float4*)bias)[ct];
  for (int tg = grp; tg < TG; tg += 2) {
    const int t = t0 + tg;
    float a0 = 0.f, a1 = 0.f, a2 = 0.f, a3 = 0.f;
#pragma unroll
    for (int j = 0; j < NK; ++j) {
      int pos = t + j - 15;
      pos = pos < 0 ? 0 : (pos > NT - 1 ? NT - 1 : pos);  // OOB taps have w==0
      const float wgt = wsm[tg][h][j];
      const float4 v = x4[(((size_t)b * NT + pos) << 7) + ct];
      a0 += wgt * v.x; a1 += wgt * v.y; a2 += wgt * v.z; a3 += wgt * v.w;
    }
    const int cs = (c4 & ~63) | ((c4 & 63) ^ ((t & 7) << 3));  // 4-aligned preserved
    union { short4v s4; __hip_bfloat16 hh[4]; } u;
    u.hh[0] = __float2bfloat16(a0 + b4.x);
    u.hh[1] = __float2bfloat16(a1 + b4.y);
    u.hh[2] = __float2bfloat16(a2 + b4.z);
    u.hh[3] = __float2bfloat16(a3 + b4.w);
    *(short4v*)(Y + ((size_t)b * NT + t) * NC + cs) = u.s4;
  }
}

// ---------------------------------------------------------------------------
// conv_gemm (R6 k-loop + transpose epilogue): 256x256 tile, 8 waves (2Mx4N).
// ONE barrier per K-step; counted lgkmcnt quadrant pipeline:
//   [issue A-lo + B-lo + B-hi] lgkm(4) [Q00 | issue A-hi] lgkm(8)
//   [Q01] lgkm(0) [Q11+Q10]; B(s+2) stage chunks spread through.
// Triple-buffered B in LDS via global_load_lds; vmcnt(4) steady state;
// vmcnt(0) only at cb starts (Ys) and final step. Swizzled Wt + Ys.
// Epilogue: selu -> LDS transpose (reuse pool) -> coalesced 16B Z stores.
// ---------------------------------------------------------------------------
__global__ __launch_bounds__(512, 2) void conv_gemm(const __hip_bfloat16* __restrict__ Y,
                                                    const __hip_bfloat16* __restrict__ Wt,
                                                    const float* __restrict__ bc,
                                                    __hip_bfloat16* __restrict__ Z) {
  const int o0 = blockIdx.x << 8;
  const int t0 = blockIdx.y << 8;
  const int b = blockIdx.z;
  __shared__ __align__(16) char pool[135168];   // Ys 36,864 + Bsm 3x32,768
  __hip_bfloat16* Ys = (__hip_bfloat16*)pool;
  __hip_bfloat16* b0 = (__hip_bfloat16*)(pool + 36864);
  __hip_bfloat16* b1 = (__hip_bfloat16*)(pool + 36864 + 32768);
  __hip_bfloat16* b2 = (__hip_bfloat16*)(pool + 36864 + 65536);
  const int tid = threadIdx.x;
  const int lane = tid & 63, wid = tid >> 6;
  const int wr = wid >> 2, wcid = wid & 3;
  const int obig = o0 >> 8;

  f32x4 acc[8][4] = {};

  auto stageY = [&](int cb_) {
    const int c0 = cb_ << 6;
#pragma unroll
    for (int p = 0; p < 5; ++p) {
      const int i = (p << 9) + tid;          // 2304 chunks of 16B = 288 rows
      if (i < 2304) {                        // wave-uniform predicate
        int grow = t0 + (i >> 3);
        if (grow > NT - 1) grow = NT - 1;    // feeds only discarded output rows
        gload_lds16(Y + (((size_t)b * NT + grow) << 9) + c0 + ((i & 7) << 3),
                    &Ys[i << 3]);
      }
    }
  };
  auto stageBc = [&](__hip_bfloat16* dst, int s_, int p) {  // one chunk (512 thr)
    const __hip_bfloat16* wb = Wt + (((size_t)(obig * 248 + s_)) << 14);
    const int i = (p << 9) + tid;            // 2048 chunks of 16B
    gload_lds16(wb + (i << 3), dst + (i << 3));
  };

  // prologue: Ys(0), B(0), B(1) in flight
  stageY(0);
#pragma unroll
  for (int p = 0; p < 4; ++p) stageBc(b0, 0, p);
#pragma unroll
  for (int p = 0; p < 4; ++p) stageBc(b1, 1, p);

  const int l15 = lane & 15;
  const int kob = (lane >> 4) << 3;       // fragment K-offset base (elements)
  const int R0 = (wr << 7) + l15;         // A base row (lane part)
  const int bkey = (l15 & 7) << 3;        // B swizzle key (k-invariant)

  // B element offsets within a buffer, per [kk][half][n] (k-invariant)
  int boff[2][2][2];
#pragma unroll
  for (int kk = 0; kk < 2; ++kk)
#pragma unroll
    for (int hf = 0; hf < 2; ++hf)
#pragma unroll
      for (int n = 0; n < 2; ++n) {
        const int br = (wcid << 6) + (hf << 5) + (n << 4) + l15;
        boff[kk][hf][n] = (br << 6) + (((kk << 5) | kob) ^ bkey);
      }

  for (int cb = 0; cb < 8; ++cb) {
    for (int k = 0; k < NK; ++k) {
      const int s = cb * 31 + k;
      const bool st = (s <= 245);

      if ((k == 0 && cb > 0) || s == 247) { WVM(0); } else { WVM(4); }
      SBAR();  // B(s) (+Ys at cb start) visible in all waves' views

      // A addressing for this k (key shared by all m: 16|64 ≡ 0 mod 8)
      const int keyv = ((l15 + k) & 7) << 3;
      const int ako0 = kob ^ keyv;
      const int ako1 = (32 | kob) ^ keyv;
      const int arow = (R0 + k) << 6;  // element offset of A-low row (+ m<<10)

      short8 av0[4], av1[4], a20[4], a21[4];
      short8 bl0[2], bl1[2], bh0[2], bh1[2];

      // ---- issue A-low + B-low + B-high (16 ds_read_b128)
#pragma unroll
      for (int m = 0; m < 4; ++m) {
        av0[m] = *(const short8*)&Ys[arow + (m << 10) + ako0];
        av1[m] = *(const short8*)&Ys[arow + (m << 10) + ako1];
      }
#pragma unroll
      for (int n = 0; n < 2; ++n) {
        bl0[n] = *(const short8*)&b0[boff[0][0][n]];
        bl1[n] = *(const short8*)&b0[boff[1][0][n]];
        bh0[n] = *(const short8*)&b0[boff[0][1][n]];
        bh1[n] = *(const short8*)&b0[boff[1][1][n]];
      }
      if (st) stageBc(b2, s + 2, 0);

      WLGKM(4);  // A-low + B-low done; B-high may lag
      __builtin_amdgcn_s_setprio(1);
#pragma unroll
      for (int m = 0; m < 4; ++m)
#pragma unroll
        for (int n = 0; n < 2; ++n)
          acc[m][n] = __builtin_amdgcn_mfma_f32_16x16x32_bf16(av0[m], bl0[n], acc[m][n], 0, 0, 0);
#pragma unroll
      for (int m = 0; m < 4; ++m)
#pragma unroll
        for (int n = 0; n < 2; ++n)
          acc[m][n] = __builtin_amdgcn_mfma_f32_16x16x32_bf16(av1[m], bl1[n], acc[m][n], 0, 0, 0);
      __builtin_amdgcn_s_setprio(0);

      if (st) stageBc(b2, s + 2, 1);
      // ---- issue A-high (8 ds_read_b128) under Q00/Q01
#pragma unroll
      for (int m = 0; m < 4; ++m) {
        a20[m] = *(const short8*)&Ys[arow + 4096 + (m << 10) + ako0];
        a21[m] = *(const short8*)&Ys[arow + 4096 + (m << 10) + ako1];
      }

      WLGKM(8);  // B-high done; A-high in flight
      __builtin_amdgcn_s_setprio(1);
#pragma unroll
      for (int m = 0; m < 4; ++m)
#pragma unroll
        for (int n = 0; n < 2; ++n)
          acc[m][2 + n] = __builtin_amdgcn_mfma_f32_16x16x32_bf16(av0[m], bh0[n], acc[m][2 + n], 0, 0, 0);
#pragma unroll
      for (int m = 0; m < 4; ++m)
#pragma unroll
        for (int n = 0; n < 2; ++n)
          acc[m][2 + n] = __builtin_amdgcn_mfma_f32_16x16x32_bf16(av1[m], bh1[n], acc[m][2 + n], 0, 0, 0);
      __builtin_amdgcn_s_setprio(0);

      if (st) stageBc(b2, s + 2, 2);

      WLGKM(0);  // A-high done; all ds_reads of this step retired
      __builtin_amdgcn_s_setprio(1);
#pragma unroll
      for (int m = 0; m < 4; ++m)
#pragma unroll
        for (int n = 0; n < 2; ++n)
          acc[4 + m][2 + n] = __builtin_amdgcn_mfma_f32_16x16x32_bf16(a20[m], bh0[n], acc[4 + m][2 + n], 0, 0, 0);
#pragma unroll
      for (int m = 0; m < 4; ++m)
#pragma unroll
        for (int n = 0; n < 2; ++n)
          acc[4 + m][2 + n] = __builtin_amdgcn_mfma_f32_16x16x32_bf16(a21[m], bh1[n], acc[4 + m][2 + n], 0, 0, 0);
#pragma unroll
      for (int m = 0; m < 4; ++m)
#pragma unroll
        for (int n = 0; n < 2; ++n)
          acc[4 + m][n] = __builtin_amdgcn_mfma_f32_16x16x32_bf16(a20[m], bl0[n], acc[4 + m][n], 0, 0, 0);
#pragma unroll
      for (int m = 0; m < 4; ++m)
#pragma unroll
        for (int n = 0; n < 2; ++n)
          acc[4 + m][n] = __builtin_amdgcn_mfma_f32_16x16x32_bf16(a21[m], bl1[n], acc[4 + m][n], 0, 0, 0);
      __builtin_amdgcn_s_setprio(0);

      if (st) stageBc(b2, s + 2, 3);

      // rotate triple buffer
      __hip_bfloat16* tp = b0; b0 = b1; b1 = b2; b2 = tp;
    }
    if (cb < 7) {
      SBAR();          // all waves' Ys reads done (each drained lgkm to 0)
      stageY(cb + 1);  // next step's vmcnt(0) waits for these
    }
  }

  // ---- epilogue: selu -> LDS transpose -> coalesced swizzled 16B stores
  SBAR();                                           // pool reusable (regs hold acc)
  __hip_bfloat16* zt = (__hip_bfloat16*)pool;       // [256][264] = 135,168 B
  const float kS = 1.0507009873554805f;
  const float kAS = 1.7580993408473766f;            // scale*alpha
  const int l15e = lane & 15;
#pragma unroll
  for (int n = 0; n < 4; ++n) {
    const int col = (wcid << 6) + (n << 4) + l15e;
    const float bcv = bc[o0 + col];
#pragma unroll
    for (int m = 0; m < 8; ++m) {
      const int rb = (wr << 7) + (m << 4) + ((lane >> 4) << 2);
#pragma unroll
      for (int r = 0; r < 4; ++r) {
        const float v = acc[m][n][r] + bcv;
        const float sv = v > 0.f ? kS * v : kAS * (__expf(v) - 1.f);
        zt[(rb + r) * 264 + col] = __float2bfloat16(sv);
      }
    }
  }
  __syncthreads();
  for (int j = tid; j < 8192; j += 512) {   // 256 rows x 32 chunks of 16B
    const int row = j >> 5;
    const int c8 = (j & 31) << 3;
    const int tp = t0 + row;
    if (tp < NTP) {
      const size_t grow = (size_t)b * NTP + tp;
      const int key = ((int)grow & 7) << 3;
      const int cs = (c8 & ~63) | ((c8 & 63) ^ key);   // 8-aligned preserved
      *(short8*)(Z + grow * NHID + o0 + cs) = *(const short8*)&zt[row * 264 + c8];
    }
  }
}

// ---------------------------------------------------------------------------
// out_gemm: Out[row,c] = sum_o Z[row,o]*W2[c,o] + b2[c]  (fp32), M=7952,N=512,K=2048
// double-buffered A+B, one barrier per step.
// ---------------------------------------------------------------------------
__global__ __launch_bounds__(256) void out_gemm(const __hip_bfloat16* __restrict__ Zm,
                                                const __hip_bfloat16* __restrict__ W2t,
                                                const float* __restrict__ b2,
                                                float* __restrict__ Out) {
  const int n0 = blockIdx.x << 7;
  const int m0 = blockIdx.y << 7;
  __shared__ __align__(16) __hip_bfloat16 As[2][128 * 64];
  __shared__ __align__(16) __hip_bfloat16 Bs[2][128 * 64];
  const int tid = threadIdx.x;
  const int lane = tid & 63, wid = tid >> 6;
  const int wr = wid >> 1, wc = wid & 1;

  auto stage = [&](int bufi, int kb_) {
#pragma unroll
    for (int p = 0; p < 4; ++p) {
      const int i = (p << 8) + tid;
      int row = m0 + (i >> 3);
      if (row > MROWS - 1) row = MROWS - 1;  // discarded rows only
      gload_lds16(Zm + ((size_t)row << 11) + (kb_ << 6) + ((i & 7) << 3),
                  &As[bufi][i << 3]);
    }
    const __hip_bfloat16* wb = W2t + ((size_t)((n0 >> 7) * 32 + kb_) << 13);
#pragma unroll
    for (int p = 0; p < 4; ++p) {
      const int i = (p << 8) + tid;
      gload_lds16(wb + (i << 3), &Bs[bufi][i << 3]);
    }
  };

  f32x4 acc[4][4] = {};
  stage(0, 0);

  for (int kb = 0; kb < 32; ++kb) {
    const int buf = kb & 1;
    __syncthreads();                 // drains vmcnt(0): stage(kb) landed; prior reads done
    if (kb < 31) stage(buf ^ 1, kb + 1);
#pragma unroll
    for (int kk = 0; kk < 2; ++kk) {
      const int ko = (kk << 5) + ((lane >> 4) << 3);
      short8 av[4], bv[4];
#pragma unroll
      for (int m = 0; m < 4; ++m) {
        const int r = (wr << 6) + (m << 4) + (lane & 15);
        av[m] = *(const short8*)&As[buf][(r << 6) + (ko ^ ((r & 7) << 3))];
      }
#pragma unroll
      for (int n = 0; n < 4; ++n) {
        const int br = (wc << 6) + (n << 4) + (lane & 15);
        bv[n] = *(const short8*)&Bs[buf][(br << 6) + (ko ^ ((br & 7) << 3))];
      }
#pragma unroll
      for (int m = 0; m < 4; ++m)
#pragma unroll
        for (int n = 0; n < 4; ++n)
          acc[m][n] = __builtin_amdgcn_mfma_f32_16x16x32_bf16(av[m], bv[n], acc[m][n], 0, 0, 0);
    }
  }

#pragma unroll
  for (int n = 0; n < 4; ++n) {
    const int col = n0 + (wc << 6) + (n << 4) + (lane & 15);
    const float b2v = b2[col];
#pragma unroll
    for (int m = 0; m < 4; ++m) {
      const int rbase = m0 + (wr << 6) + (m << 4) + ((lane >> 4) << 2);
#pragma unroll
      for (int r = 0; r < 4; ++r) {
        const int row = rbase + r;
        if (row < MROWS) Out[(size_t)row * NC + col] = acc[m][n][r] + b2v;
      }
    }
  }
}

// ---------------------------------------------------------------------------
extern "C" void kernel_launch(void* const* d_in, const int* in_sizes, int n_in,
                              void* d_out, int out_size, void* d_ws, size_t ws_size,
                              hipStream_t stream) {
  const float* x = (const float*)d_in[0];
  const float* Wl = (const float*)d_in[1];
  const float* bl = (const float*)d_in[2];
  const float* bias = (const float*)d_in[3];
  const float* Wc = (const float*)d_in[4];
  const float* bc = (const float*)d_in[5];
  const float* W2 = (const float*)d_in[6];
  const float* b2 = (const float*)d_in[7];
  float* out = (float*)d_out;

  char* ws = (char*)d_ws;
  __hip_bfloat16* Wt = (__hip_bfloat16*)(ws);                    // 31*8*2048*64*2 = 65,011,712
  __hip_bfloat16* Y = (__hip_bfloat16*)(ws + 65011712);          // 8*1024*512*2   =  8,388,608
  __hip_bfloat16* W2t = (__hip_bfloat16*)(ws + 73400320);        // 32*512*64*2    =  2,097,152
  __hip_bfloat16* Z = (__hip_bfloat16*)(ws + 75497472);          // 8*994*2048*2   = 32,571,392

  hipLaunchKernelGGL(prep_wc, dim3(2048), dim3(256), 0, stream, Wc, Wt);
  hipLaunchKernelGGL(prep_w2, dim3(4096), dim3(256), 0, stream, W2, W2t);
  hipLaunchKernelGGL(dynconv, dim3(NT / TG, NB), dim3(256), 0, stream, x, Wl, bl, bias, Y);
  hipLaunchKernelGGL(conv_gemm, dim3(NHID / 256, 4, NB), dim3(512), 0, stream, Y, Wt, bc, Z);
  hipLaunchKernelGGL(out_gemm, dim3(NC / 128, (MROWS + 127) / 128), dim3(256), 0, stream,
                     Z, W2t, b2, out);
}